// Round 6
// baseline (1283.095 us; speedup 1.0000x reference)
//
#include <hip/hip_runtime.h>

typedef __attribute__((ext_vector_type(4))) float   f32x4;
typedef __attribute__((ext_vector_type(8))) __bf16  bf16x8;
typedef unsigned short u16;
typedef __attribute__((ext_vector_type(8))) unsigned short u16x8;
typedef __attribute__((ext_vector_type(4))) unsigned short u16x4;

__device__ __forceinline__ u16 f2bf(float f) {
  unsigned u = __builtin_bit_cast(unsigned, f);
  u += 0x7fffu + ((u >> 16) & 1u);
  return (u16)(u >> 16);
}
__device__ __forceinline__ float bf2f(u16 h) {
  unsigned u = ((unsigned)h) << 16;
  return __builtin_bit_cast(float, u);
}
__device__ __forceinline__ void gld16(const void* g, void* l) {
  __builtin_amdgcn_global_load_lds(
      (const __attribute__((address_space(1))) void*)g,
      (__attribute__((address_space(3))) void*)l, 16, 0, 0);
}

#define SB __builtin_amdgcn_sched_barrier(0)
#define SYNC_MID do { SB; __builtin_amdgcn_s_barrier(); \
  asm volatile("s_waitcnt lgkmcnt(0)" ::: "memory"); SB; } while(0)
#define SYNC_END do { SB; __builtin_amdgcn_s_barrier(); SB; } while(0)
#define VM8 do { SB; asm volatile("s_waitcnt vmcnt(8)" ::: "memory"); SB; } while(0)
#define VM0 do { SB; asm volatile("s_waitcnt vmcnt(0)" ::: "memory"); SB; } while(0)

// ============================================================================
// KV projection: 8-phase 256x256 tile, BK=64, *4 waves* (wave tile 128x128,
// acc[8][8] in AGPRs) -> LDS reads per K-tile drop to 32 b128/wave
// (128 KB/block vs 192 KB at 8 waves). M-batched: one block = one (n-panel,
// batch), 64 K-tiles streamed, prologue paid once, epilogue every 8 tiles.
// A = xb (bf16, from cvt_x), B = Wkv; both via global_load_lds w16 with
// slot^(row&7) swizzle (R4-proven, 0 conflicts). Counted VM8 at ph4/ph8
// (retires the 2 half-tiles needed next, leaves newest 2 in flight);
// VM0 only at the tail. XCD map pins a batch's 4 n-panels to one XCD.
// ============================================================================
__global__ __launch_bounds__(256, 1)
void kv8_k(const u16* __restrict__ xb, const u16* __restrict__ Wkv,
           u16* __restrict__ Kc, u16* __restrict__ Vt)
{
  __shared__ u16 SM[65536];   // A: [2 slot][2 half][128][64] @0, B same @32768
  const int t = threadIdx.x;
  const int w = t >> 6, lane = t & 63;
  const int wr = w >> 1, wc = w & 1;
  const int lr = lane & 15, lc = lane >> 4;

  int bx, by;
  if (gridDim.y == 64) {      // XCD c gets batches by with by&7==c, all 4 panels
    const int h = (int)(blockIdx.y * 4 + blockIdx.x);
    const int c = h & 7, i = h >> 3;
    by = c + (i & 7) * 8;
    bx = i >> 3;
  } else { bx = blockIdx.x; by = blockIdx.y; }
  const int n0 = bx * 256;
  const u16* xg = xb + (long)by * 2048 * 512;

  f32x4 acc[8][8];
#pragma unroll
  for (int i = 0; i < 8; i++)
#pragma unroll
    for (int j = 0; j < 8; j++) acc[i][j] = f32x4{0.f, 0.f, 0.f, 0.f};
  u16x8 bq[8][2];

  auto stageA = [&](int TT, int h) {   // 128x64 bf16 half-tile, 4 gld16/thread
#pragma unroll
    for (int r = 0; r < 4; ++r) {
      const int c = r * 256 + t;
      const int row = c >> 3, slot = c & 7;
      const u16* g = xg + (long)((TT >> 3) * 256 + h * 128 + row) * 512
                        + (TT & 7) * 64 + ((slot ^ (row & 7)) * 8);
      gld16(g, (void*)&SM[((TT & 1) * 2 + h) * 8192 + c * 8]);
    }
  };
  auto stageB = [&](int TT, int h) {
#pragma unroll
    for (int r = 0; r < 4; ++r) {
      const int c = r * 256 + t;
      const int row = c >> 3, slot = c & 7;
      const u16* g = Wkv + (long)(n0 + h * 128 + row) * 512
                         + (TT & 7) * 64 + ((slot ^ (row & 7)) * 8);
      gld16(g, (void*)&SM[32768 + ((TT & 1) * 2 + h) * 8192 + c * 8]);
    }
  };
  auto ldb = [&](int S) {              // full B tile for wave's 128 cols
#pragma unroll
    for (int j = 0; j < 8; ++j)
#pragma unroll
      for (int s = 0; s < 2; ++s) {
        const int rl = j * 16 + lr;
        bq[j][s] = *(const u16x8*)&SM[32768 + (S * 2 + wc) * 8192 + rl * 64
                                      + (((s * 4 + lc) ^ (rl & 7)) * 8)];
      }
  };
  auto lda = [&](u16x8 (&aq)[2][2], int S, int I0) {
#pragma unroll
    for (int f = 0; f < 2; ++f)
#pragma unroll
      for (int s = 0; s < 2; ++s) {
        const int rl = (I0 + f) * 16 + lr;
        aq[f][s] = *(const u16x8*)&SM[(S * 2 + wr) * 8192 + rl * 64
                                      + (((s * 4 + lc) ^ (rl & 7)) * 8)];
      }
  };
  auto mm = [&](u16x8 (&aq)[2][2], int I0) {
    __builtin_amdgcn_s_setprio(1);
#pragma unroll
    for (int f = 0; f < 2; ++f)
#pragma unroll
      for (int j = 0; j < 8; ++j)
#pragma unroll
        for (int s = 0; s < 2; ++s)
          acc[I0 + f][j] = __builtin_amdgcn_mfma_f32_16x16x32_bf16(
              __builtin_bit_cast(bf16x8, aq[f][s]), __builtin_bit_cast(bf16x8, bq[j][s]),
              acc[I0 + f][j], 0, 0, 0);
    __builtin_amdgcn_s_setprio(0);
  };
  auto epi = [&](int mt) {
#pragma unroll
    for (int i = 0; i < 8; i++)
#pragma unroll
      for (int j = 0; j < 8; j++) {
        const int ml = mt * 256 + wr * 128 + i * 16 + lc * 4;
        const int n  = n0 + wc * 128 + j * 16 + lr;
        if (n0 < 512) {
#pragma unroll
          for (int ii = 0; ii < 4; ii++)
            Kc[((long)by * 2048 + ml + ii) * 512 + n] = f2bf(acc[i][j][ii]);
        } else {
          u16x4 hh;
#pragma unroll
          for (int ii = 0; ii < 4; ii++) hh[ii] = f2bf(acc[i][j][ii]);
          *(u16x4*)(Vt + ((long)by * 512 + (n - 512)) * 2048 + ml) = hh;
        }
        acc[i][j] = f32x4{0.f, 0.f, 0.f, 0.f};
      }
  };

  // prologue: A(0) both halves, B(0), B(1); A(0)+B(0) landed, B(1) in flight
  stageA(0, 0); stageA(0, 1);
  stageB(0, 0); stageB(0, 1);
  stageB(1, 0); stageB(1, 1);
  VM8;
  __builtin_amdgcn_s_barrier(); SB;

  const int NT = 64;   // 8 m-tiles x 8 K-tiles
#pragma unroll 1
  for (int I = 0; I < NT / 2; ++I) {
    const int a = 2 * I, b = 2 * I + 1;
    const bool g2 = (a + 2) < NT;
    const bool g3 = (b + 2) < NT;
    // ---- tile a (slot 0) ----
    { u16x8 aq[2][2]; ldb(0); lda(aq, 0, 0); stageA(b, 0);
      SYNC_MID; mm(aq, 0); SYNC_END; }
    { u16x8 aq[2][2]; lda(aq, 0, 2); stageA(b, 1);
      SYNC_MID; mm(aq, 2); SYNC_END; }
    { u16x8 aq[2][2]; lda(aq, 0, 4); if (g2) stageB(a + 2, 0);
      SYNC_MID; mm(aq, 4); SYNC_END; }
    { u16x8 aq[2][2]; lda(aq, 0, 6); if (g2) stageB(a + 2, 1);
      SYNC_MID; mm(aq, 6); if (g2) { VM8; } else { VM0; } SYNC_END; }
    // ---- tile b (slot 1) ----
    { u16x8 aq[2][2]; ldb(1); lda(aq, 1, 0); if (g2) stageA(a + 2, 0);
      SYNC_MID; mm(aq, 0); SYNC_END; }
    { u16x8 aq[2][2]; lda(aq, 1, 2); if (g2) stageA(a + 2, 1);
      SYNC_MID; mm(aq, 2); SYNC_END; }
    { u16x8 aq[2][2]; lda(aq, 1, 4); if (g3) stageB(b + 2, 0);
      SYNC_MID; mm(aq, 4); SYNC_END; }
    { u16x8 aq[2][2]; lda(aq, 1, 6); if (g3) stageB(b + 2, 1);
      SYNC_MID; mm(aq, 6); if (g3) { VM8; } else { VM0; } SYNC_END; }
    if ((I & 3) == 3) epi(I >> 2);
  }
}

// ============================================================================
// Proven 2-buffer 128^2 GEMM (bf16 A): Q-proj, scores, PV.
// EPI: 0 = bf16 store, 2 = scores(scale+mask), 3 = relu f32
// ============================================================================
template<int EPI>
__global__ __launch_bounds__(256)
void gemm_k(const u16* __restrict__ Ap, const u16* __restrict__ Bp,
            void* __restrict__ Cp, const int* __restrict__ maskp,
            int K, long sA, long sB, long sC, long sM, int ldc, float scale)
{
  __shared__ u16 Asb[2][4096];
  __shared__ u16 Bs [2][4096];

  const int t = threadIdx.x, z = blockIdx.z;
  const int n0 = blockIdx.x * 128, m0 = blockIdx.y * 128;
  const int KT = K / 32;
  const u16* Ab = Ap + (long)z * sA;
  const u16* Bb = Bp + (long)z * sB;

  const int w = t >> 6, lane = t & 63;
  const int m0w = (w >> 1) * 64, n0w = (w & 1) * 64;
  const int lr = lane & 15, lc = lane >> 4;

  f32x4 acc[4][4];
#pragma unroll
  for (int i = 0; i < 4; i++)
#pragma unroll
    for (int j = 0; j < 4; j++) acc[i][j] = f32x4{0.f, 0.f, 0.f, 0.f};

  auto stage = [&](int buf, int kt) {
#pragma unroll
    for (int i = 0; i < 2; i++) {
      int chunk = w * 2 + i, row = chunk * 16 + (lane >> 2), cc = lane & 3;
      const u16* g = Ab + (long)(m0 + row) * K + kt * 32 + ((cc ^ ((row >> 1) & 3)) << 3);
      gld16(g, (void*)&Asb[buf][chunk * 512]);
    }
#pragma unroll
    for (int i = 0; i < 2; i++) {
      int chunk = w * 2 + i, row = chunk * 16 + (lane >> 2), cc = lane & 3;
      const u16* g = Bb + (long)(n0 + row) * K + kt * 32 + ((cc ^ ((row >> 1) & 3)) << 3);
      gld16(g, (void*)&Bs[buf][chunk * 512]);
    }
  };
  auto compute = [&](int buf) {
    bf16x8 af[4], bv[4];
#pragma unroll
    for (int f = 0; f < 4; f++) {
      const int R = m0w + f * 16 + lr;
      af[f] = __builtin_bit_cast(bf16x8,
          *(const u16x8*)&Asb[buf][R * 32 + ((lc ^ ((R >> 1) & 3)) << 3)]);
      const int R2 = n0w + f * 16 + lr;
      bv[f] = __builtin_bit_cast(bf16x8,
          *(const u16x8*)&Bs[buf][R2 * 32 + ((lc ^ ((R2 >> 1) & 3)) << 3)]);
    }
#pragma unroll
    for (int i = 0; i < 4; i++)
#pragma unroll
      for (int j = 0; j < 4; j++)
        acc[i][j] = __builtin_amdgcn_mfma_f32_16x16x32_bf16(af[i], bv[j], acc[i][j], 0, 0, 0);
  };

  stage(0, 0);
  __syncthreads();
  int cur = 0;
  for (int kt = 1; kt < KT; ++kt) {
    stage(cur ^ 1, kt);
    compute(cur);
    __syncthreads();
    cur ^= 1;
  }
  compute(cur);

#pragma unroll
  for (int i = 0; i < 4; i++) {
#pragma unroll
    for (int j = 0; j < 4; j++) {
      const int mb = m0 + m0w + i * 16 + lc * 4;
      const int n  = n0 + n0w + j * 16 + lr;
      if constexpr (EPI == 0) {
        u16* C = (u16*)Cp + (long)z * sC;
#pragma unroll
        for (int ii = 0; ii < 4; ii++)
          C[(long)(mb + ii) * ldc + n] = f2bf(acc[i][j][ii]);
      } else if constexpr (EPI == 2) {
        const int* mk = maskp + (long)z * sM;
        u16* C = (u16*)Cp + (long)z * sC;
        const float bias = mk[n] ? 0.f : -1e10f;
#pragma unroll
        for (int ii = 0; ii < 4; ii++)
          C[(long)(mb + ii) * ldc + n] = f2bf(acc[i][j][ii] * scale + bias);
      } else {
        float* C = (float*)Cp + (long)z * sC;
#pragma unroll
        for (int ii = 0; ii < 4; ii++)
          C[(long)(mb + ii) * ldc + n] = fmaxf(acc[i][j][ii], 0.f);
      }
    }
  }
}

// convert + concat [Wq;Wk;Wv] f32 [3*512,512] -> bf16
__global__ __launch_bounds__(256)
void wconv_k(const float* __restrict__ Wq, const float* __restrict__ Wk,
             const float* __restrict__ Wv, u16* __restrict__ Wb)
{
  long i4 = (long)blockIdx.x * 256 + threadIdx.x;
  long e  = i4 * 4;
  const float* W = (e < 262144) ? Wq : (e < 524288 ? Wk : Wv);
  long off = e & 262143;
  f32x4 f = *(const f32x4*)(W + off);
  u16x4 h;
#pragma unroll
  for (int j = 0; j < 4; j++) h[j] = f2bf(f[j]);
  *(u16x4*)(Wb + e) = h;
}

// f32 -> bf16, 8 elems/thread
__global__ __launch_bounds__(256)
void cvt_k(const float* __restrict__ in, u16* __restrict__ out)
{
  long i = ((long)blockIdx.x * 256 + threadIdx.x) * 8;
  f32x4 a = *(const f32x4*)(in + i);
  f32x4 b = *(const f32x4*)(in + i + 4);
  u16x8 h;
#pragma unroll
  for (int j = 0; j < 4; j++) { h[j] = f2bf(a[j]); h[4 + j] = f2bf(b[j]); }
  *(u16x8*)(out + i) = h;
}

// in-place row softmax over 2048 bf16 logits
__global__ __launch_bounds__(256)
void softmax_k(u16* __restrict__ S)
{
  const long row = blockIdx.x;
  const int  t   = threadIdx.x;
  u16* R = S + row * 2048;
  u16x8 v = *(const u16x8*)(R + t * 8);
  float f[8];
#pragma unroll
  for (int j = 0; j < 8; j++) f[j] = bf2f(v[j]);
  float m = f[0];
#pragma unroll
  for (int j = 1; j < 8; j++) m = fmaxf(m, f[j]);
#pragma unroll
  for (int off = 32; off > 0; off >>= 1) m = fmaxf(m, __shfl_xor(m, off));
  __shared__ float red[4], red2[4];
  const int w = t >> 6;
  if ((t & 63) == 0) red[w] = m;
  __syncthreads();
  m = fmaxf(fmaxf(red[0], red[1]), fmaxf(red[2], red[3]));
  float e[8], s = 0.f;
#pragma unroll
  for (int j = 0; j < 8; j++) { e[j] = __expf(f[j] - m); s += e[j]; }
#pragma unroll
  for (int off = 32; off > 0; off >>= 1) s += __shfl_xor(s, off);
  if ((t & 63) == 0) red2[w] = s;
  __syncthreads();
  s = red2[0] + red2[1] + red2[2] + red2[3];
  const float inv = 1.f / s;
  u16x8 o;
#pragma unroll
  for (int j = 0; j < 8; j++) o[j] = f2bf(e[j] * inv);
  *(u16x8*)(R + t * 8) = o;
}

extern "C" void kernel_launch(void* const* d_in, const int* in_sizes, int n_in,
                              void* d_out, int out_size, void* d_ws, size_t ws_size,
                              hipStream_t stream)
{
  const float* mf   = (const float*)d_in[0];   // [64,128,512]
  const float* x    = (const float*)d_in[1];   // [64,2048,512]
  const int*   mask = (const int*)d_in[2];     // [64,2048]
  const float* Wq   = (const float*)d_in[3];
  const float* Wk   = (const float*)d_in[4];
  const float* Wv   = (const float*)d_in[5];
  float* out = (float*)d_out;

  u16* ws  = (u16*)d_ws;
  u16* Wb  = ws;                     // 1536*512 = 786432 u16
  u16* mfb = Wb + 786432;            // 8192*512 = 4194304 u16
  u16* Qb  = mfb + 4194304;          // 8192*512 = 4194304 u16
  u16* dyn = Qb + 4194304;

  // per-batch: xb(2MB) + K(2MB) + Vt(2MB) + S(0.5MB) = 6815744 B
  const size_t fixedB = (size_t)(786432 + 4194304 + 4194304) * 2;
  int CB = 64;
  while (CB > 1 && fixedB + (size_t)CB * 6815744ull > ws_size) CB >>= 1;

  u16* xbc = dyn;                               // [CB*2048, 512] bf16
  u16* Kc  = xbc + (size_t)CB * 1048576;        // [CB*2048, 512]
  u16* Vtc = Kc  + (size_t)CB * 1048576;        // [CB, 512, 2048]
  u16* Sc  = Vtc + (size_t)CB * 1048576;        // [CB, 128, 2048]

  const float scale = 0.044194173824159216f;    // 1/sqrt(512)

  wconv_k<<<768, 256, 0, stream>>>(Wq, Wk, Wv, Wb);
  cvt_k<<<2048, 256, 0, stream>>>(mf, mfb);

  // Q projection: M=8192, N=512, K=512
  gemm_k<0><<<dim3(4, 64, 1), 256, 0, stream>>>(
      mfb, Wb, Qb, nullptr, 512, 0, 0, 0, 0, 512, 1.f);

  for (int bc = 0; bc < 64; bc += CB) {
    const float* xc = x + (long)bc * 2048 * 512;
    cvt_k<<<CB * 512, 256, 0, stream>>>(xc, xbc);
    // fused K+V projection: M-batched 4-wave 8-phase 256^2
    kv8_k<<<dim3(4, CB, 1), 256, 0, stream>>>(xbc, Wb + 262144, Kc, Vtc);
    // scores: S[q,kv] = (Q K^T)*scale - (1-mask)*1e10  (bf16)
    gemm_k<2><<<dim3(16, 1, CB), 256, 0, stream>>>(
        Qb + (long)bc * 65536, Kc, Sc, mask + (long)bc * 2048,
        512, 65536, 1048576, 262144, 2048, 2048, scale);
    softmax_k<<<CB * 128, 256, 0, stream>>>(Sc);
    // PV: out = relu(P V^T), K=2048, f32 out
    gemm_k<3><<<dim3(4, 1, CB), 256, 0, stream>>>(
        Sc, Vtc, out + (long)bc * 65536, nullptr,
        2048, 262144, 1048576, 65536, 0, 512, 1.f);
  }
}

// Round 8
// 392.049 us; speedup vs baseline: 3.2728x; 3.2728x over previous
//
#include <hip/hip_runtime.h>

typedef __attribute__((ext_vector_type(4))) float   f32x4;
typedef __attribute__((ext_vector_type(8))) __bf16  bf16x8;
typedef unsigned short u16;
typedef __attribute__((ext_vector_type(8))) unsigned short u16x8;
typedef __attribute__((ext_vector_type(4))) unsigned short u16x4;

__device__ __forceinline__ u16 f2bf(float f) {
  unsigned u = __builtin_bit_cast(unsigned, f);
  u += 0x7fffu + ((u >> 16) & 1u);
  return (u16)(u >> 16);
}
__device__ __forceinline__ float bf2f(u16 h) {
  unsigned u = ((unsigned)h) << 16;
  return __builtin_bit_cast(float, u);
}
__device__ __forceinline__ void gld16(const void* g, void* l) {
  __builtin_amdgcn_global_load_lds(
      (const __attribute__((address_space(1))) void*)g,
      (__attribute__((address_space(3))) void*)l, 16, 0, 0);
}

// ============================================================================
// KV projection: R4 8-wave 8-phase 256x256/BK=64 kernel + M-batching.
// FIX vs R7: all waits are vmcnt(4) (R7's VM8 prologue left B(0) in flight
// when ph1 read it -> absmax 0.101). VM4 ledger (2 gld16 per half-stage):
//   prologue: 12 out -> retire 8 = A(0),B(0) landed; B(1) in flight.
//   ph4 VM4: retires A(b) staged ph1/2  -> ph5's LDA(slot1) safe.
//   ph8 VM4: retires A(a+2) ph5/6 + B(a+2) ph3/4 -> next ph1 LDA/LDB safe.
// Every ds_read now provably reads landed data (no empirical races).
// ============================================================================

#define SB __builtin_amdgcn_sched_barrier(0)
#define SYNC_MID do { SB; __builtin_amdgcn_s_barrier(); \
  asm volatile("s_waitcnt lgkmcnt(0)" ::: "memory"); SB; } while(0)
#define SYNC_END do { SB; __builtin_amdgcn_s_barrier(); SB; } while(0)
#define VM4 do { SB; asm volatile("s_waitcnt vmcnt(4)" ::: "memory"); SB; } while(0)
#define VM0 do { SB; asm volatile("s_waitcnt vmcnt(0)" ::: "memory"); SB; } while(0)

#define LDA(AQ, S, I0) \
  _Pragma("unroll") for (int f = 0; f < 2; ++f) \
  _Pragma("unroll") for (int s = 0; s < 2; ++s) { \
    const int rl = ((I0)+f)*16 + lr; \
    AQ[f*2+s] = *(const u16x8*)&SM[((S)*2 + wr)*8192 + rl*64 + (((s*4+lc) ^ (rl&7))*8)]; }

#define LDB(S) \
  _Pragma("unroll") for (int j = 0; j < 4; ++j) \
  _Pragma("unroll") for (int s = 0; s < 2; ++s) { \
    const int rl = (wc&1)*64 + j*16 + lr; \
    bq[j][s] = *(const u16x8*)&SM[32768 + ((S)*2 + (wc>>1))*8192 + rl*64 + (((s*4+lc) ^ (rl&7))*8)]; }

#define MM(AQ, I0) do { __builtin_amdgcn_s_setprio(1); \
  _Pragma("unroll") for (int f = 0; f < 2; ++f) \
  _Pragma("unroll") for (int j = 0; j < 4; ++j) \
  _Pragma("unroll") for (int s = 0; s < 2; ++s) \
    acc[(I0)+f][j] = __builtin_amdgcn_mfma_f32_16x16x32_bf16( \
      __builtin_bit_cast(bf16x8, AQ[f*2+s]), __builtin_bit_cast(bf16x8, bq[j][s]), \
      acc[(I0)+f][j], 0, 0, 0); \
  __builtin_amdgcn_s_setprio(0); } while(0)

__global__ __launch_bounds__(512, 1)
void kv8_k(const u16* __restrict__ xb, const u16* __restrict__ Wkv,
           u16* __restrict__ Kc, u16* __restrict__ Vt)
{
  __shared__ u16 SM[65536];   // A: [2 slot][2 half][128][64] @0, B same @32768
  const int t = threadIdx.x;
  const int w = t >> 6, lane = t & 63;
  const int wr = w >> 2, wc = w & 3;
  const int lr = lane & 15, lc = lane >> 4;

  int bx, by;
  if (gridDim.y == 64) {
    // linear id h -> XCD h&7; XCD c executes batches {by: by&7==c}, all 4
    // panels of a batch on one XCD (bijective: 8c x 8(i&7) x 4(i>>3) = 256).
    const int h = (int)(blockIdx.y * 4 + blockIdx.x);
    const int c = h & 7, i = h >> 3;
    by = c + 8 * (i & 7);
    bx = i >> 3;
  } else { bx = blockIdx.x; by = blockIdx.y; }
  const int n0 = bx * 256;
  const u16* xg = xb + (long)by * 2048 * 512;

  f32x4 acc[8][4];
#pragma unroll
  for (int i = 0; i < 8; i++)
#pragma unroll
    for (int j = 0; j < 4; j++) acc[i][j] = f32x4{0.f, 0.f, 0.f, 0.f};
  u16x8 bq[4][2];

  auto stageA = [&](int TT, int h) {   // 128x64 half-tile, 2 gld16/thread (512 thr)
#pragma unroll
    for (int r = 0; r < 2; ++r) {
      const int c = r * 512 + t;
      const int row = c >> 3, slot = c & 7;
      const u16* g = xg + (long)((TT >> 3) * 256 + h * 128 + row) * 512
                        + (TT & 7) * 64 + ((slot ^ (row & 7)) * 8);
      gld16(g, (void*)&SM[((TT & 1) * 2 + h) * 8192 + c * 8]);
    }
  };
  auto stageB = [&](int TT, int h) {
#pragma unroll
    for (int r = 0; r < 2; ++r) {
      const int c = r * 512 + t;
      const int row = c >> 3, slot = c & 7;
      const u16* g = Wkv + (long)(n0 + h * 128 + row) * 512
                         + (TT & 7) * 64 + ((slot ^ (row & 7)) * 8);
      gld16(g, (void*)&SM[32768 + ((TT & 1) * 2 + h) * 8192 + c * 8]);
    }
  };
  auto epi = [&](int mt) {
#pragma unroll
    for (int i = 0; i < 8; i++)
#pragma unroll
      for (int j = 0; j < 4; j++) {
        const int ml = mt * 256 + wr * 128 + i * 16 + lc * 4;
        const int n  = n0 + wc * 64 + j * 16 + lr;
        if (n0 < 512) {
#pragma unroll
          for (int ii = 0; ii < 4; ii++)
            Kc[((long)by * 2048 + ml + ii) * 512 + n] = f2bf(acc[i][j][ii]);
        } else {
          u16x4 hh;
#pragma unroll
          for (int ii = 0; ii < 4; ii++) hh[ii] = f2bf(acc[i][j][ii]);
          *(u16x4*)(Vt + ((long)by * 512 + (n - 512)) * 2048 + ml) = hh;
        }
        acc[i][j] = f32x4{0.f, 0.f, 0.f, 0.f};
      }
  };

  // prologue: A(0), B(0), B(1) issued; VM4 -> A(0)+B(0) landed, B(1) in flight
  stageA(0, 0); stageA(0, 1);
  stageB(0, 0); stageB(0, 1);
  stageB(1, 0); stageB(1, 1);
  VM4;
  __builtin_amdgcn_s_barrier(); SB;

  const int NT = 64;   // 8 m-tiles x 8 K-tiles, continuous stream
#pragma unroll 1
  for (int I = 0; I < NT / 2; ++I) {
    const int a = 2 * I, b = 2 * I + 1;
    const bool g2 = (a + 2) < NT;
    const bool g3 = (b + 2) < NT;
    // ---- tile a (slot 0) ----
    { u16x8 aq[4]; LDB(0); LDA(aq, 0, 0); stageA(b, 0);
      SYNC_MID; MM(aq, 0); SYNC_END; }
    { u16x8 aq[4]; LDA(aq, 0, 2); stageA(b, 1);
      SYNC_MID; MM(aq, 2); SYNC_END; }
    { u16x8 aq[4]; LDA(aq, 0, 4); if (g2) stageB(a + 2, 0);
      SYNC_MID; MM(aq, 4); SYNC_END; }
    { u16x8 aq[4]; LDA(aq, 0, 6); if (g2) stageB(a + 2, 1);
      SYNC_MID; MM(aq, 6); if (g2) { VM4; } else { VM0; } SYNC_END; }
    // ---- tile b (slot 1) ----
    { u16x8 aq[4]; LDB(1); LDA(aq, 1, 0); if (g2) stageA(a + 2, 0);
      SYNC_MID; MM(aq, 0); SYNC_END; }
    { u16x8 aq[4]; LDA(aq, 1, 2); if (g2) stageA(a + 2, 1);
      SYNC_MID; MM(aq, 2); SYNC_END; }
    { u16x8 aq[4]; LDA(aq, 1, 4); if (g3) stageB(b + 2, 0);
      SYNC_MID; MM(aq, 4); SYNC_END; }
    { u16x8 aq[4]; LDA(aq, 1, 6); if (g3) stageB(b + 2, 1);
      SYNC_MID; MM(aq, 6); if (g3) { VM4; } else { VM0; } SYNC_END; }
    if ((I & 3) == 3) epi(I >> 2);
  }
}

// ============================================================================
// Proven 2-buffer 128^2 GEMM (bf16 A): Q-proj, scores, PV.
// EPI: 0 = bf16 store, 2 = scores(scale+mask), 3 = relu f32
// ============================================================================
template<int EPI>
__global__ __launch_bounds__(256)
void gemm_k(const u16* __restrict__ Ap, const u16* __restrict__ Bp,
            void* __restrict__ Cp, const int* __restrict__ maskp,
            int K, long sA, long sB, long sC, long sM, int ldc, float scale)
{
  __shared__ u16 Asb[2][4096];
  __shared__ u16 Bs [2][4096];

  const int t = threadIdx.x, z = blockIdx.z;
  const int n0 = blockIdx.x * 128, m0 = blockIdx.y * 128;
  const int KT = K / 32;
  const u16* Ab = Ap + (long)z * sA;
  const u16* Bb = Bp + (long)z * sB;

  const int w = t >> 6, lane = t & 63;
  const int m0w = (w >> 1) * 64, n0w = (w & 1) * 64;
  const int lr = lane & 15, lc = lane >> 4;

  f32x4 acc[4][4];
#pragma unroll
  for (int i = 0; i < 4; i++)
#pragma unroll
    for (int j = 0; j < 4; j++) acc[i][j] = f32x4{0.f, 0.f, 0.f, 0.f};

  auto stage = [&](int buf, int kt) {
#pragma unroll
    for (int i = 0; i < 2; i++) {
      int chunk = w * 2 + i, row = chunk * 16 + (lane >> 2), cc = lane & 3;
      const u16* g = Ab + (long)(m0 + row) * K + kt * 32 + ((cc ^ ((row >> 1) & 3)) << 3);
      gld16(g, (void*)&Asb[buf][chunk * 512]);
    }
#pragma unroll
    for (int i = 0; i < 2; i++) {
      int chunk = w * 2 + i, row = chunk * 16 + (lane >> 2), cc = lane & 3;
      const u16* g = Bb + (long)(n0 + row) * K + kt * 32 + ((cc ^ ((row >> 1) & 3)) << 3);
      gld16(g, (void*)&Bs[buf][chunk * 512]);
    }
  };
  auto compute = [&](int buf) {
    bf16x8 af[4], bv[4];
#pragma unroll
    for (int f = 0; f < 4; f++) {
      const int R = m0w + f * 16 + lr;
      af[f] = __builtin_bit_cast(bf16x8,
          *(const u16x8*)&Asb[buf][R * 32 + ((lc ^ ((R >> 1) & 3)) << 3)]);
      const int R2 = n0w + f * 16 + lr;
      bv[f] = __builtin_bit_cast(bf16x8,
          *(const u16x8*)&Bs[buf][R2 * 32 + ((lc ^ ((R2 >> 1) & 3)) << 3)]);
    }
#pragma unroll
    for (int i = 0; i < 4; i++)
#pragma unroll
      for (int j = 0; j < 4; j++)
        acc[i][j] = __builtin_amdgcn_mfma_f32_16x16x32_bf16(af[i], bv[j], acc[i][j], 0, 0, 0);
  };

  stage(0, 0);
  __syncthreads();
  int cur = 0;
  for (int kt = 1; kt < KT; ++kt) {
    stage(cur ^ 1, kt);
    compute(cur);
    __syncthreads();
    cur ^= 1;
  }
  compute(cur);

#pragma unroll
  for (int i = 0; i < 4; i++) {
#pragma unroll
    for (int j = 0; j < 4; j++) {
      const int mb = m0 + m0w + i * 16 + lc * 4;
      const int n  = n0 + n0w + j * 16 + lr;
      if constexpr (EPI == 0) {
        u16* C = (u16*)Cp + (long)z * sC;
#pragma unroll
        for (int ii = 0; ii < 4; ii++)
          C[(long)(mb + ii) * ldc + n] = f2bf(acc[i][j][ii]);
      } else if constexpr (EPI == 2) {
        const int* mk = maskp + (long)z * sM;
        u16* C = (u16*)Cp + (long)z * sC;
        const float bias = mk[n] ? 0.f : -1e10f;
#pragma unroll
        for (int ii = 0; ii < 4; ii++)
          C[(long)(mb + ii) * ldc + n] = f2bf(acc[i][j][ii] * scale + bias);
      } else {
        float* C = (float*)Cp + (long)z * sC;
#pragma unroll
        for (int ii = 0; ii < 4; ii++)
          C[(long)(mb + ii) * ldc + n] = fmaxf(acc[i][j][ii], 0.f);
      }
    }
  }
}

// convert + concat [Wq;Wk;Wv] f32 [3*512,512] -> bf16
__global__ __launch_bounds__(256)
void wconv_k(const float* __restrict__ Wq, const float* __restrict__ Wk,
             const float* __restrict__ Wv, u16* __restrict__ Wb)
{
  long i4 = (long)blockIdx.x * 256 + threadIdx.x;
  long e  = i4 * 4;
  const float* W = (e < 262144) ? Wq : (e < 524288 ? Wk : Wv);
  long off = e & 262143;
  f32x4 f = *(const f32x4*)(W + off);
  u16x4 h;
#pragma unroll
  for (int j = 0; j < 4; j++) h[j] = f2bf(f[j]);
  *(u16x4*)(Wb + e) = h;
}

// f32 -> bf16, 8 elems/thread
__global__ __launch_bounds__(256)
void cvt_k(const float* __restrict__ in, u16* __restrict__ out)
{
  long i = ((long)blockIdx.x * 256 + threadIdx.x) * 8;
  f32x4 a = *(const f32x4*)(in + i);
  f32x4 b = *(const f32x4*)(in + i + 4);
  u16x8 h;
#pragma unroll
  for (int j = 0; j < 4; j++) { h[j] = f2bf(a[j]); h[4 + j] = f2bf(b[j]); }
  *(u16x8*)(out + i) = h;
}

// in-place row softmax over 2048 bf16 logits
__global__ __launch_bounds__(256)
void softmax_k(u16* __restrict__ S)
{
  const long row = blockIdx.x;
  const int  t   = threadIdx.x;
  u16* R = S + row * 2048;
  u16x8 v = *(const u16x8*)(R + t * 8);
  float f[8];
#pragma unroll
  for (int j = 0; j < 8; j++) f[j] = bf2f(v[j]);
  float m = f[0];
#pragma unroll
  for (int j = 1; j < 8; j++) m = fmaxf(m, f[j]);
#pragma unroll
  for (int off = 32; off > 0; off >>= 1) m = fmaxf(m, __shfl_xor(m, off));
  __shared__ float red[4], red2[4];
  const int w = t >> 6;
  if ((t & 63) == 0) red[w] = m;
  __syncthreads();
  m = fmaxf(fmaxf(red[0], red[1]), fmaxf(red[2], red[3]));
  float e[8], s = 0.f;
#pragma unroll
  for (int j = 0; j < 8; j++) { e[j] = __expf(f[j] - m); s += e[j]; }
#pragma unroll
  for (int off = 32; off > 0; off >>= 1) s += __shfl_xor(s, off);
  if ((t & 63) == 0) red2[w] = s;
  __syncthreads();
  s = red2[0] + red2[1] + red2[2] + red2[3];
  const float inv = 1.f / s;
  u16x8 o;
#pragma unroll
  for (int j = 0; j < 8; j++) o[j] = f2bf(e[j] * inv);
  *(u16x8*)(R + t * 8) = o;
}

extern "C" void kernel_launch(void* const* d_in, const int* in_sizes, int n_in,
                              void* d_out, int out_size, void* d_ws, size_t ws_size,
                              hipStream_t stream)
{
  const float* mf   = (const float*)d_in[0];   // [64,128,512]
  const float* x    = (const float*)d_in[1];   // [64,2048,512]
  const int*   mask = (const int*)d_in[2];     // [64,2048]
  const float* Wq   = (const float*)d_in[3];
  const float* Wk   = (const float*)d_in[4];
  const float* Wv   = (const float*)d_in[5];
  float* out = (float*)d_out;

  u16* ws  = (u16*)d_ws;
  u16* Wb  = ws;                     // 1536*512 = 786432 u16
  u16* mfb = Wb + 786432;            // 8192*512 = 4194304 u16
  u16* Qb  = mfb + 4194304;          // 8192*512 = 4194304 u16
  u16* dyn = Qb + 4194304;

  // per-batch: xb(2MB) + K(2MB) + Vt(2MB) + S(0.5MB) = 6815744 B
  const size_t fixedB = (size_t)(786432 + 4194304 + 4194304) * 2;
  int CB = 64;
  while (CB > 1 && fixedB + (size_t)CB * 6815744ull > ws_size) CB >>= 1;

  u16* xbc = dyn;                               // [CB*2048, 512] bf16
  u16* Kc  = xbc + (size_t)CB * 1048576;        // [CB*2048, 512]
  u16* Vtc = Kc  + (size_t)CB * 1048576;        // [CB, 512, 2048]
  u16* Sc  = Vtc + (size_t)CB * 1048576;        // [CB, 128, 2048]

  const float scale = 0.044194173824159216f;    // 1/sqrt(512)

  wconv_k<<<768, 256, 0, stream>>>(Wq, Wk, Wv, Wb);
  cvt_k<<<2048, 256, 0, stream>>>(mf, mfb);

  // Q projection: M=8192, N=512, K=512
  gemm_k<0><<<dim3(4, 64, 1), 256, 0, stream>>>(
      mfb, Wb, Qb, nullptr, 512, 0, 0, 0, 0, 512, 1.f);

  for (int bc = 0; bc < 64; bc += CB) {
    const float* xc = x + (long)bc * 2048 * 512;
    cvt_k<<<CB * 512, 256, 0, stream>>>(xc, xbc);
    // fused K+V projection: M-batched 8-wave 8-phase 256^2 (VM4-proven)
    kv8_k<<<dim3(4, CB, 1), 512, 0, stream>>>(xbc, Wb + 262144, Kc, Vtc);
    // scores: S[q,kv] = (Q K^T)*scale - (1-mask)*1e10  (bf16)
    gemm_k<2><<<dim3(16, 1, CB), 256, 0, stream>>>(
        Qb + (long)bc * 65536, Kc, Sc, mask + (long)bc * 2048,
        512, 65536, 1048576, 262144, 2048, 2048, scale);
    softmax_k<<<CB * 128, 256, 0, stream>>>(Sc);
    // PV: out = relu(P V^T), K=2048, f32 out
    gemm_k<3><<<dim3(4, 1, CB), 256, 0, stream>>>(
        Sc, Vtc, out + (long)bc * 65536, nullptr,
        2048, 262144, 1048576, 65536, 0, 512, 1.f);
  }
}